// Round 1
// baseline (532.522 us; speedup 1.0000x reference)
//
#include <hip/hip_runtime.h>

// GCN: 3-layer GraphConv (norm='right'), N=50000 nodes, E=600000 edges,
// dims 128 -> 128 -> 128 -> 64. fp32 throughout.
//
// Strategy:
//   build CSR by dst (deg count -> prefix sum -> bucket fill)  [once per call]
//   L1: agg128(features)->B0 ; gemm128(B0,W1,b1,relu)->B1
//   L2: agg128(B1)->B0       ; gemm128(B0,W2,b2,relu)->B1
//   L3: gemm64(B1,W3,nobias) ->B0(T) ; agg64(T)+b3 -> d_out
// No float atomics anywhere.

#define N_NODES 50000
#define N_EDGES 600000

// ---------------- CSR build ----------------

__global__ void count_deg_k(const int* __restrict__ dst, int* __restrict__ deg, int e) {
    int i = blockIdx.x * blockDim.x + threadIdx.x;
    if (i < e) atomicAdd(&deg[dst[i]], 1);
}

__global__ void inv_deg_k(const int* __restrict__ deg, float* __restrict__ inv, int n) {
    int i = blockIdx.x * blockDim.x + threadIdx.x;
    if (i < n) {
        int d = deg[i];
        inv[i] = 1.0f / (float)(d > 0 ? d : 1);
    }
}

// single-block chunked exclusive prefix sum over deg -> offs[0..n], cursor copy
__global__ __launch_bounds__(1024) void scan_k(const int* __restrict__ deg,
                                               int* __restrict__ offs,
                                               int* __restrict__ cursor, int n) {
    constexpr int T = 1024;
    __shared__ int sums[T];
    int t = threadIdx.x;
    int chunk = (n + T - 1) / T;
    int s = t * chunk;
    int e = s + chunk; if (e > n) e = n;
    int sum = 0;
    for (int i = s; i < e; ++i) sum += deg[i];
    sums[t] = sum;
    __syncthreads();
    // Hillis-Steele inclusive scan
    for (int off = 1; off < T; off <<= 1) {
        int x = (t >= off) ? sums[t - off] : 0;
        __syncthreads();
        sums[t] += x;
        __syncthreads();
    }
    int run = sums[t] - sum;  // exclusive prefix of this thread's chunk
    for (int i = s; i < e; ++i) {
        offs[i] = run;
        cursor[i] = run;
        run += deg[i];
    }
    if (t == T - 1) offs[n] = run;
}

__global__ void fill_csr_k(const int* __restrict__ src, const int* __restrict__ dst,
                           int* __restrict__ cursor, int* __restrict__ esrc, int e) {
    int i = blockIdx.x * blockDim.x + threadIdx.x;
    if (i < e) {
        int p = atomicAdd(&cursor[dst[i]], 1);
        esrc[p] = src[i];
    }
}

// ---------------- aggregation (one wave per node) ----------------

// 128-wide: each lane owns 2 consecutive floats (float2), 512B coalesced row reads
__global__ __launch_bounds__(256) void agg128_k(const float* __restrict__ h,
                                                const int* __restrict__ offs,
                                                const int* __restrict__ esrc,
                                                const float* __restrict__ inv,
                                                float* __restrict__ out, int n) {
    int wid = (int)((blockIdx.x * blockDim.x + threadIdx.x) >> 6);
    int lane = threadIdx.x & 63;
    if (wid >= n) return;
    int beg = offs[wid], end = offs[wid + 1];
    const float2* __restrict__ h2 = (const float2*)h;
    float ax = 0.f, ay = 0.f;
    int j = beg;
    for (; j + 2 <= end; j += 2) {
        int s0 = esrc[j], s1 = esrc[j + 1];
        float2 v0 = h2[(size_t)s0 * 64 + lane];
        float2 v1 = h2[(size_t)s1 * 64 + lane];
        ax += v0.x + v1.x;
        ay += v0.y + v1.y;
    }
    if (j < end) {
        float2 v = h2[(size_t)esrc[j] * 64 + lane];
        ax += v.x; ay += v.y;
    }
    float sc = inv[wid];
    float2 r; r.x = ax * sc; r.y = ay * sc;
    ((float2*)out)[(size_t)wid * 64 + lane] = r;
}

// 64-wide: lane owns 1 float; fused bias add; writes final output
__global__ __launch_bounds__(256) void agg64_k(const float* __restrict__ t64,
                                               const int* __restrict__ offs,
                                               const int* __restrict__ esrc,
                                               const float* __restrict__ inv,
                                               const float* __restrict__ bias,
                                               float* __restrict__ out, int n) {
    int wid = (int)((blockIdx.x * blockDim.x + threadIdx.x) >> 6);
    int lane = threadIdx.x & 63;
    if (wid >= n) return;
    int beg = offs[wid], end = offs[wid + 1];
    float a = 0.f;
    int j = beg;
    for (; j + 2 <= end; j += 2) {
        int s0 = esrc[j], s1 = esrc[j + 1];
        a += t64[(size_t)s0 * 64 + lane] + t64[(size_t)s1 * 64 + lane];
    }
    if (j < end) a += t64[(size_t)esrc[j] * 64 + lane];
    out[(size_t)wid * 64 + lane] = a * inv[wid] + bias[lane];
}

// ---------------- GEMM: [M,128] x [128,NCOLS] (+bias, +relu) ----------------
// block 256 threads; each thread: 2 rows x 16 cols. K staged in 4 tiles of 32.

template <int NCOLS, bool HASB, bool RELU>
__global__ __launch_bounds__(256) void gemm_k(const float* __restrict__ A,
                                              const float* __restrict__ W,
                                              const float* __restrict__ bias,
                                              float* __restrict__ out, int M) {
    constexpr int CG = NCOLS / 16;   // col groups: 8 (128) or 4 (64)
    constexpr int RP = 256 / CG;     // row pairs per block: 32 or 64
    constexpr int ROWS = 2 * RP;     // 64 or 128
    __shared__ float As[ROWS][33];
    __shared__ float Ws[32][NCOLS];
    int t = threadIdx.x;
    int cg = t % CG, rp = t / CG;
    int rowbase = blockIdx.x * ROWS;
    float acc0[16], acc1[16];
#pragma unroll
    for (int c = 0; c < 16; ++c) { acc0[c] = 0.f; acc1[c] = 0.f; }

    for (int kt = 0; kt < 4; ++kt) {
        for (int idx = t; idx < ROWS * 32; idx += 256) {
            int r = idx >> 5, c = idx & 31;
            int gr = rowbase + r;
            As[r][c] = (gr < M) ? A[(size_t)gr * 128 + kt * 32 + c] : 0.f;
        }
        for (int idx = t; idx < 32 * NCOLS; idx += 256) {
            int r = idx / NCOLS, c = idx % NCOLS;
            Ws[r][c] = W[(size_t)(kt * 32 + r) * NCOLS + c];
        }
        __syncthreads();
#pragma unroll 8
        for (int kk = 0; kk < 32; ++kk) {
            float a0 = As[2 * rp][kk];
            float a1 = As[2 * rp + 1][kk];
#pragma unroll
            for (int c = 0; c < 16; ++c) {
                float w = Ws[kk][cg * 16 + c];
                acc0[c] = fmaf(a0, w, acc0[c]);
                acc1[c] = fmaf(a1, w, acc1[c]);
            }
        }
        __syncthreads();
    }

    int r0 = rowbase + 2 * rp, r1 = r0 + 1;
    int cb = cg * 16;
#pragma unroll
    for (int c = 0; c < 16; ++c) {
        float v0 = acc0[c], v1 = acc1[c];
        if (HASB) { float b = bias[cb + c]; v0 += b; v1 += b; }
        if (RELU) { v0 = fmaxf(v0, 0.f); v1 = fmaxf(v1, 0.f); }
        acc0[c] = v0; acc1[c] = v1;
    }
    if (r0 < M) {
#pragma unroll
        for (int c = 0; c < 16; ++c) out[(size_t)r0 * NCOLS + cb + c] = acc0[c];
    }
    if (r1 < M) {
#pragma unroll
        for (int c = 0; c < 16; ++c) out[(size_t)r1 * NCOLS + cb + c] = acc1[c];
    }
}

// ---------------- launch ----------------

extern "C" void kernel_launch(void* const* d_in, const int* in_sizes, int n_in,
                              void* d_out, int out_size, void* d_ws, size_t ws_size,
                              hipStream_t stream) {
    const int N = N_NODES, E = N_EDGES;
    const float* feat = (const float*)d_in[0];
    const int* src = (const int*)d_in[1];
    const int* dst = (const int*)d_in[2];
    const float* W1 = (const float*)d_in[3];
    const float* b1 = (const float*)d_in[4];
    const float* W2 = (const float*)d_in[5];
    const float* b2 = (const float*)d_in[6];
    const float* W3 = (const float*)d_in[7];
    const float* b3 = (const float*)d_in[8];
    float* out = (float*)d_out;

    // workspace layout (all 4-byte aligned)
    float* B0 = (float*)d_ws;                       // N*128
    float* B1 = B0 + (size_t)N * 128;               // N*128
    int* deg = (int*)(B1 + (size_t)N * 128);        // N
    float* invd = (float*)(deg + N);                // N
    int* offs = (int*)(invd + N);                   // N+1
    int* cursor = offs + N + 1;                     // N
    int* esrc = cursor + N;                         // E

    // --- CSR build ---
    hipMemsetAsync(deg, 0, (size_t)N * sizeof(int), stream);
    count_deg_k<<<(E + 255) / 256, 256, 0, stream>>>(dst, deg, E);
    inv_deg_k<<<(N + 255) / 256, 256, 0, stream>>>(deg, invd, N);
    scan_k<<<1, 1024, 0, stream>>>(deg, offs, cursor, N);
    fill_csr_k<<<(E + 255) / 256, 256, 0, stream>>>(src, dst, cursor, esrc, E);

    const int aggGrid = (N + 3) / 4;  // 4 waves (nodes) per 256-thread block

    // --- layer 1 ---
    agg128_k<<<aggGrid, 256, 0, stream>>>(feat, offs, esrc, invd, B0, N);
    gemm_k<128, true, true><<<(N + 63) / 64, 256, 0, stream>>>(B0, W1, b1, B1, N);
    // --- layer 2 ---
    agg128_k<<<aggGrid, 256, 0, stream>>>(B1, offs, esrc, invd, B0, N);
    gemm_k<128, true, true><<<(N + 63) / 64, 256, 0, stream>>>(B0, W2, b2, B1, N);
    // --- layer 3: T = B1 @ W3 (no bias), then 64-wide aggregate + b3 ---
    gemm_k<64, false, false><<<(N + 127) / 128, 256, 0, stream>>>(B1, W3, nullptr, B0, N);
    agg64_k<<<aggGrid, 256, 0, stream>>>(B0, offs, esrc, invd, b3, out, N);
}

// Round 3
// 441.755 us; speedup vs baseline: 1.2055x; 1.2055x over previous
//
#include <hip/hip_runtime.h>

// GCN: 3-layer GraphConv (norm='right'), N=50000 nodes, E=600000 edges,
// dims 128 -> 128 -> 128 -> 64. fp32 throughout.
//
//   build CSR by dst (deg count -> hierarchical scan -> bucket fill)
//   L1: agg128(features)->B0 ; gemm128(B0,W1,b1,relu)->B1
//   L2: agg128(B1)->B0       ; gemm128(B0,W2,b2,relu)->B1
//   L3: gemm64(B1,W3,nobias) ->B0(T) ; agg64(T)+b3 -> d_out
// No float atomics anywhere.
//
// R1: replaced single-block serial scan (110 us, 0.14% occupancy) with a
// 3-kernel hierarchical scan (partial sums -> scan block sums -> local scan).
// R2: resubmit (GPU acquisition timeout, no data).

#define N_NODES 50000
#define N_EDGES 600000
#define SCAN_CHUNK 1024  // elements per block in the hierarchical scan

// ---------------- CSR build ----------------

__global__ void count_deg_k(const int* __restrict__ dst, int* __restrict__ deg, int e) {
    int i = blockIdx.x * blockDim.x + threadIdx.x;
    if (i < e) atomicAdd(&deg[dst[i]], 1);
}

__global__ void inv_deg_k(const int* __restrict__ deg, float* __restrict__ inv, int n) {
    int i = blockIdx.x * blockDim.x + threadIdx.x;
    if (i < n) {
        int d = deg[i];
        inv[i] = 1.0f / (float)(d > 0 ? d : 1);
    }
}

// (A) per-block sums over SCAN_CHUNK elements
__global__ __launch_bounds__(256) void scan_part_k(const int* __restrict__ deg,
                                                   int* __restrict__ blockSums, int n) {
    __shared__ int red[256];
    int t = threadIdx.x;
    int base = blockIdx.x * SCAN_CHUNK + t * 4;
    int s = 0;
#pragma unroll
    for (int k = 0; k < 4; ++k) {
        int i = base + k;
        if (i < n) s += deg[i];
    }
    red[t] = s;
    __syncthreads();
    for (int off = 128; off > 0; off >>= 1) {
        if (t < off) red[t] += red[t + off];
        __syncthreads();
    }
    if (t == 0) blockSums[blockIdx.x] = red[0];
}

// (B) serial exclusive scan of block sums (nb ~ 49); also writes offs[n] = total
__global__ void scan_blocks_k(int* __restrict__ blockSums, int nb,
                              int* __restrict__ offs, int n) {
    if (threadIdx.x == 0 && blockIdx.x == 0) {
        int run = 0;
        for (int i = 0; i < nb; ++i) {
            int v = blockSums[i];
            blockSums[i] = run;
            run += v;
        }
        offs[n] = run;
    }
}

// (C) local exclusive scan + block offset -> offs, cursor
__global__ __launch_bounds__(256) void scan_final_k(const int* __restrict__ deg,
                                                    const int* __restrict__ blockSums,
                                                    int* __restrict__ offs,
                                                    int* __restrict__ cursor, int n) {
    __shared__ int red[256];
    int t = threadIdx.x;
    int base = blockIdx.x * SCAN_CHUNK + t * 4;
    int v[4];
    int s = 0;
#pragma unroll
    for (int k = 0; k < 4; ++k) {
        int i = base + k;
        v[k] = (i < n) ? deg[i] : 0;
        s += v[k];
    }
    red[t] = s;
    __syncthreads();
    // Hillis-Steele inclusive scan of thread sums
    for (int off = 1; off < 256; off <<= 1) {
        int x = (t >= off) ? red[t - off] : 0;
        __syncthreads();
        red[t] += x;
        __syncthreads();
    }
    int run = blockSums[blockIdx.x] + red[t] - s;  // exclusive prefix for this thread
#pragma unroll
    for (int k = 0; k < 4; ++k) {
        int i = base + k;
        if (i < n) {
            offs[i] = run;
            cursor[i] = run;
            run += v[k];
        }
    }
}

__global__ void fill_csr_k(const int* __restrict__ src, const int* __restrict__ dst,
                           int* __restrict__ cursor, int* __restrict__ esrc, int e) {
    int i = blockIdx.x * blockDim.x + threadIdx.x;
    if (i < e) {
        int p = atomicAdd(&cursor[dst[i]], 1);
        esrc[p] = src[i];
    }
}

// ---------------- aggregation (one wave per node) ----------------

// 128-wide: each lane owns 2 consecutive floats (float2), 512B coalesced row reads
__global__ __launch_bounds__(256) void agg128_k(const float* __restrict__ h,
                                                const int* __restrict__ offs,
                                                const int* __restrict__ esrc,
                                                const float* __restrict__ inv,
                                                float* __restrict__ out, int n) {
    int wid = (int)((blockIdx.x * blockDim.x + threadIdx.x) >> 6);
    int lane = threadIdx.x & 63;
    if (wid >= n) return;
    int beg = offs[wid], end = offs[wid + 1];
    const float2* __restrict__ h2 = (const float2*)h;
    float ax = 0.f, ay = 0.f;
    int j = beg;
    for (; j + 2 <= end; j += 2) {
        int s0 = esrc[j], s1 = esrc[j + 1];
        float2 v0 = h2[(size_t)s0 * 64 + lane];
        float2 v1 = h2[(size_t)s1 * 64 + lane];
        ax += v0.x + v1.x;
        ay += v0.y + v1.y;
    }
    if (j < end) {
        float2 v = h2[(size_t)esrc[j] * 64 + lane];
        ax += v.x; ay += v.y;
    }
    float sc = inv[wid];
    float2 r; r.x = ax * sc; r.y = ay * sc;
    ((float2*)out)[(size_t)wid * 64 + lane] = r;
}

// 64-wide: lane owns 1 float; fused bias add; writes final output
__global__ __launch_bounds__(256) void agg64_k(const float* __restrict__ t64,
                                               const int* __restrict__ offs,
                                               const int* __restrict__ esrc,
                                               const float* __restrict__ inv,
                                               const float* __restrict__ bias,
                                               float* __restrict__ out, int n) {
    int wid = (int)((blockIdx.x * blockDim.x + threadIdx.x) >> 6);
    int lane = threadIdx.x & 63;
    if (wid >= n) return;
    int beg = offs[wid], end = offs[wid + 1];
    float a = 0.f;
    int j = beg;
    for (; j + 2 <= end; j += 2) {
        int s0 = esrc[j], s1 = esrc[j + 1];
        a += t64[(size_t)s0 * 64 + lane] + t64[(size_t)s1 * 64 + lane];
    }
    if (j < end) a += t64[(size_t)esrc[j] * 64 + lane];
    out[(size_t)wid * 64 + lane] = a * inv[wid] + bias[lane];
}

// ---------------- GEMM: [M,128] x [128,NCOLS] (+bias, +relu) ----------------
// block 256 threads; each thread: 2 rows x 16 cols. K staged in 4 tiles of 32.

template <int NCOLS, bool HASB, bool RELU>
__global__ __launch_bounds__(256) void gemm_k(const float* __restrict__ A,
                                              const float* __restrict__ W,
                                              const float* __restrict__ bias,
                                              float* __restrict__ out, int M) {
    constexpr int CG = NCOLS / 16;   // col groups: 8 (128) or 4 (64)
    constexpr int RP = 256 / CG;     // row pairs per block: 32 or 64
    constexpr int ROWS = 2 * RP;     // 64 or 128
    __shared__ float As[ROWS][33];
    __shared__ float Ws[32][NCOLS];
    int t = threadIdx.x;
    int cg = t % CG, rp = t / CG;
    int rowbase = blockIdx.x * ROWS;
    float acc0[16], acc1[16];
#pragma unroll
    for (int c = 0; c < 16; ++c) { acc0[c] = 0.f; acc1[c] = 0.f; }

    for (int kt = 0; kt < 4; ++kt) {
        for (int idx = t; idx < ROWS * 32; idx += 256) {
            int r = idx >> 5, c = idx & 31;
            int gr = rowbase + r;
            As[r][c] = (gr < M) ? A[(size_t)gr * 128 + kt * 32 + c] : 0.f;
        }
        for (int idx = t; idx < 32 * NCOLS; idx += 256) {
            int r = idx / NCOLS, c = idx % NCOLS;
            Ws[r][c] = W[(size_t)(kt * 32 + r) * NCOLS + c];
        }
        __syncthreads();
#pragma unroll 8
        for (int kk = 0; kk < 32; ++kk) {
            float a0 = As[2 * rp][kk];
            float a1 = As[2 * rp + 1][kk];
#pragma unroll
            for (int c = 0; c < 16; ++c) {
                float w = Ws[kk][cg * 16 + c];
                acc0[c] = fmaf(a0, w, acc0[c]);
                acc1[c] = fmaf(a1, w, acc1[c]);
            }
        }
        __syncthreads();
    }

    int r0 = rowbase + 2 * rp, r1 = r0 + 1;
    int cb = cg * 16;
#pragma unroll
    for (int c = 0; c < 16; ++c) {
        float v0 = acc0[c], v1 = acc1[c];
        if (HASB) { float b = bias[cb + c]; v0 += b; v1 += b; }
        if (RELU) { v0 = fmaxf(v0, 0.f); v1 = fmaxf(v1, 0.f); }
        acc0[c] = v0; acc1[c] = v1;
    }
    if (r0 < M) {
#pragma unroll
        for (int c = 0; c < 16; ++c) out[(size_t)r0 * NCOLS + cb + c] = acc0[c];
    }
    if (r1 < M) {
#pragma unroll
        for (int c = 0; c < 16; ++c) out[(size_t)r1 * NCOLS + cb + c] = acc1[c];
    }
}

// ---------------- launch ----------------

extern "C" void kernel_launch(void* const* d_in, const int* in_sizes, int n_in,
                              void* d_out, int out_size, void* d_ws, size_t ws_size,
                              hipStream_t stream) {
    const int N = N_NODES, E = N_EDGES;
    const float* feat = (const float*)d_in[0];
    const int* src = (const int*)d_in[1];
    const int* dst = (const int*)d_in[2];
    const float* W1 = (const float*)d_in[3];
    const float* b1 = (const float*)d_in[4];
    const float* W2 = (const float*)d_in[5];
    const float* b2 = (const float*)d_in[6];
    const float* W3 = (const float*)d_in[7];
    const float* b3 = (const float*)d_in[8];
    float* out = (float*)d_out;

    const int nScanBlocks = (N + SCAN_CHUNK - 1) / SCAN_CHUNK;  // 49

    // workspace layout (all 4-byte aligned)
    float* B0 = (float*)d_ws;                       // N*128
    float* B1 = B0 + (size_t)N * 128;               // N*128
    int* deg = (int*)(B1 + (size_t)N * 128);        // N
    float* invd = (float*)(deg + N);                // N
    int* offs = (int*)(invd + N);                   // N+1
    int* cursor = offs + N + 1;                     // N
    int* esrc = cursor + N;                         // E
    int* blockSums = esrc + E;                      // nScanBlocks

    // --- CSR build ---
    hipMemsetAsync(deg, 0, (size_t)N * sizeof(int), stream);
    count_deg_k<<<(E + 255) / 256, 256, 0, stream>>>(dst, deg, E);
    inv_deg_k<<<(N + 255) / 256, 256, 0, stream>>>(deg, invd, N);
    scan_part_k<<<nScanBlocks, 256, 0, stream>>>(deg, blockSums, N);
    scan_blocks_k<<<1, 64, 0, stream>>>(blockSums, nScanBlocks, offs, N);
    scan_final_k<<<nScanBlocks, 256, 0, stream>>>(deg, blockSums, offs, cursor, N);
    fill_csr_k<<<(E + 255) / 256, 256, 0, stream>>>(src, dst, cursor, esrc, E);

    const int aggGrid = (N + 3) / 4;  // 4 waves (nodes) per 256-thread block

    // --- layer 1 ---
    agg128_k<<<aggGrid, 256, 0, stream>>>(feat, offs, esrc, invd, B0, N);
    gemm_k<128, true, true><<<(N + 63) / 64, 256, 0, stream>>>(B0, W1, b1, B1, N);
    // --- layer 2 ---
    agg128_k<<<aggGrid, 256, 0, stream>>>(B1, offs, esrc, invd, B0, N);
    gemm_k<128, true, true><<<(N + 63) / 64, 256, 0, stream>>>(B0, W2, b2, B1, N);
    // --- layer 3: T = B1 @ W3 (no bias), then 64-wide aggregate + b3 ---
    gemm_k<64, false, false><<<(N + 127) / 128, 256, 0, stream>>>(B1, W3, nullptr, B0, N);
    agg64_k<<<aggGrid, 256, 0, stream>>>(B0, offs, esrc, invd, b3, out, N);
}